// Round 19
// baseline (207.051 us; speedup 1.0000x reference)
//
#include <hip/hip_runtime.h>

// TemporalAttention, algebraically folded; single fused per-16-row kernel.
//   builder: Msw/Psw weight folds.
//   k_fused (1024 thr = 16 waves, 16 rows/block, q~/v~ live in LDS):
//     P1: q~[16][896] = bf16(q) @ Mmat (MFMA; 56 N-tiles over 16 waves)
//     P2: attn, wave w owns row w; compacted unmasked-neighbor list walked
//         with 2-stage rotating prefetch (loads in flight during compute);
//         all-masked rows unified via q=0 (uniform softmax = jnp semantics)
//     P3: X = v~ @ Pmat + bias + residual + LN (MFMA; 17 tiles / 16 waves)
// Column layout jj' = h*448 + j (j<444 valid, pads zeroed via Msw/Psw).

namespace {
constexpr int kB = 16384;
constexpr int kN = 20;
constexpr float kScale = 0.08574929257125441f;  // 1/sqrt(136)
constexpr float kLnEps = 1e-5f;
constexpr int kQS = 904;  // LDS row stride (ushort); 1808B -> 2-way banks max

// ws byte offsets
constexpr size_t kOffMsw = 0;                // ushort[56*9*64*8]
constexpr size_t kOffPsw = kOffMsw + 516096; // ushort[17*28*64*8]

constexpr int kMswBlocks = 56 * 9 * 8;       // 4032
constexpr int kPswBlocks = 17 * 28 * 8;      // 3808
}  // namespace

typedef __attribute__((ext_vector_type(8))) short s8v;
typedef __attribute__((ext_vector_type(4))) float f4v;

__device__ __forceinline__ unsigned short f2bf(float x) {
  unsigned int u = __float_as_uint(x);
  unsigned int r = (u + 0x7FFFu + ((u >> 16) & 1u)) >> 16;
  return (unsigned short)r;
}
__device__ __forceinline__ float bf2f(unsigned short h) {
  return __uint_as_float(((unsigned int)h) << 16);
}
__device__ __forceinline__ float fma4(float4 a, float4 b, float acc) {
  acc = fmaf(a.x, b.x, acc);
  acc = fmaf(a.y, b.y, acc);
  acc = fmaf(a.z, b.z, acc);
  acc = fmaf(a.w, b.w, acc);
  return acc;
}
__device__ __forceinline__ s8v pack8(float4 lo, float4 hi) {
  s8v a;
  a[0] = (short)f2bf(lo.x); a[1] = (short)f2bf(lo.y);
  a[2] = (short)f2bf(lo.z); a[3] = (short)f2bf(lo.w);
  a[4] = (short)f2bf(hi.x); a[5] = (short)f2bf(hi.y);
  a[6] = (short)f2bf(hi.z); a[7] = (short)f2bf(hi.w);
  return a;
}

// ---- DPP wave64 sum (VALU only; full sum lands in lane 63) ----
__device__ __forceinline__ float dpp_sum(float x) {
  int v = __float_as_int(x), t;
  t = __builtin_amdgcn_update_dpp(0, v, 0x111, 0xf, 0xf, true);  // row_shr:1
  v = __float_as_int(__int_as_float(v) + __int_as_float(t));
  t = __builtin_amdgcn_update_dpp(0, v, 0x112, 0xf, 0xf, true);  // row_shr:2
  v = __float_as_int(__int_as_float(v) + __int_as_float(t));
  t = __builtin_amdgcn_update_dpp(0, v, 0x114, 0xf, 0xf, true);  // row_shr:4
  v = __float_as_int(__int_as_float(v) + __int_as_float(t));
  t = __builtin_amdgcn_update_dpp(0, v, 0x118, 0xf, 0xf, true);  // row_shr:8
  v = __float_as_int(__int_as_float(v) + __int_as_float(t));
  t = __builtin_amdgcn_update_dpp(0, v, 0x142, 0xf, 0xf, true);  // row_bcast:15
  v = __float_as_int(__int_as_float(v) + __int_as_float(t));
  t = __builtin_amdgcn_update_dpp(0, v, 0x143, 0xf, 0xf, true);  // row_bcast:31
  v = __float_as_int(__int_as_float(v) + __int_as_float(t));
  return __int_as_float(v);
}
__device__ __forceinline__ float rdl63(float x) {
  return __int_as_float(__builtin_amdgcn_readlane(__float_as_int(x), 63));
}
__device__ __forceinline__ float rfl(float x) {
  return __int_as_float(__builtin_amdgcn_readfirstlane(__float_as_int(x)));
}

// Merged weight-fold: blocks [0, kMswBlocks) build Msw, rest build Psw.
__global__ __launch_bounds__(64) void k_build_mp(const float* __restrict__ WQ,
                                                 const float* __restrict__ WK,
                                                 const float* __restrict__ WO,
                                                 const float* __restrict__ WV,
                                                 unsigned short* __restrict__ Msw,
                                                 unsigned short* __restrict__ Psw) {
  const int l = threadIdx.x;
  if (blockIdx.x < kMswBlocks) {
    const int bid = blockIdx.x;
    const int e = bid % 8;
    const int ks = (bid / 8) % 9;
    const int tile = bid / 72;
    const int jj = tile * 16 + (l & 15);
    const int h = jj / 448;
    const int j = jj - h * 448;
    const int i = ks * 32 + (l >> 4) * 8 + e;
    float s = 0.f;
    if (j < 444 && i < 272) {
      const float* wq = WQ + h * 136 * 272 + i;
      const float* wk = WK + h * 136 * 444 + j;
#pragma unroll 8
      for (int d = 0; d < 136; ++d) s = fmaf(wq[d * 272], wk[d * 444], s);
    }
    Msw[((size_t)(tile * 9 + ks) * 64 + l) * 8 + e] = f2bf(s);
  } else {
    const int bid = blockIdx.x - kMswBlocks;
    const int e = bid % 8;
    const int ks = (bid / 8) % 28;
    const int tile = bid / 224;
    const int n = tile * 16 + (l & 15);
    const int k = ks * 32 + (l >> 4) * 8 + e;
    const int h = k / 448;
    const int j = k - h * 448;
    float s = 0.f;
    if (j < 444) {
      const float* wo = WO + (size_t)n * 272 + h * 136;
      const float* wv = WV + h * 136 * 444 + j;
#pragma unroll 8
      for (int d = 0; d < 136; ++d) s = fmaf(wo[d], wv[d * 444], s);
    }
    Psw[((size_t)(tile * 28 + ks) * 64 + l) * 8 + e] = f2bf(s);
  }
}

// Fused 16-row pipeline; 16 waves; q~/v~ in LDS only.
__global__ __launch_bounds__(1024, 8) void k_fused(const float* __restrict__ node,
                                                   const float* __restrict__ timef,
                                                   const float* __restrict__ nnode,
                                                   const float* __restrict__ nedge,
                                                   const float* __restrict__ ntime,
                                                   const int* __restrict__ mask,
                                                   const unsigned short* __restrict__ Msw,
                                                   const unsigned short* __restrict__ Psw,
                                                   const float* __restrict__ bO,
                                                   const float* __restrict__ g,
                                                   const float* __restrict__ be,
                                                   float* __restrict__ out) {
  __shared__ unsigned short qlds[16 * kQS];  // 28,928 B; reused as LN stage
  const int tid = threadIdx.x;
  const int l = tid & 63, w = tid >> 6;  // w in 0..15
  const int m0 = blockIdx.x * 16;
  const float4 z4 = make_float4(0.f, 0.f, 0.f, 0.f);

  // ===== P1: q~ = bf16(q) @ Mmat -> qlds ================================
  {
    const int mrow = m0 + (l & 15);
    const int koff = (l >> 4) * 8;
    const float4* n4 = reinterpret_cast<const float4*>(node + (size_t)mrow * 172);
    const float4* t4 = reinterpret_cast<const float4*>(timef + (size_t)mrow * 100);
    f4v acc[4];
#pragma unroll
    for (int i = 0; i < 4; ++i) acc[i] = (f4v){0.f, 0.f, 0.f, 0.f};
    for (int ks = 0; ks < 9; ++ks) {
      const int c0 = ks * 32 + koff;
      float4 lo = z4, hi = z4;
      if (c0 + 8 <= 172) {
        lo = n4[c0 / 4];
        hi = n4[c0 / 4 + 1];
      } else if (c0 == 168) {
        lo = n4[42];
        hi = t4[0];
      } else if (c0 + 8 <= 272) {
        lo = t4[(c0 - 172) / 4];
        hi = t4[(c0 - 172) / 4 + 1];
      }
      const s8v a = pack8(lo, hi);
#pragma unroll
      for (int i = 0; i < 4; ++i) {
        const int t = w + 16 * i;
        if (t < 56) {
          const s8v b = *reinterpret_cast<const s8v*>(Msw + ((size_t)(t * 9 + ks) * 64 + l) * 8);
          acc[i] = __builtin_amdgcn_mfma_f32_16x16x32_bf16(a, b, acc[i], 0, 0, 0);
        }
      }
    }
    const int r0 = (l >> 4) * 4;
#pragma unroll
    for (int i = 0; i < 4; ++i) {
      const int t = w + 16 * i;
      if (t < 56) {
        const int n = t * 16 + (l & 15);
#pragma unroll
        for (int r = 0; r < 4; ++r) qlds[(size_t)(r0 + r) * kQS + n] = f2bf(acc[i][r]);
      }
    }
  }
  __syncthreads();

  // ===== P2: attn, wave w -> row m0+w; compact list + rotating prefetch ==
  {
    const int b = m0 + w;
    const bool v1 = (l < 47);
    const float4* nnode4 = reinterpret_cast<const float4*>(nnode);
    const float4* nedge4 = reinterpret_cast<const float4*>(nedge);
    const float4* ntime4 = reinterpret_cast<const float4*>(ntime);
    unsigned short* qrow = qlds + (size_t)w * kQS;
    const int* mrow = mask + (size_t)b * kN;

    unsigned mbits = 0;
#pragma unroll
    for (int n = 0; n < kN; ++n) mbits |= (mrow[n] != 0 ? 1u : 0u) << n;
    // All-masked: scores uniform -> softmax = 1/20 average. Achieved exactly
    // by zeroing q (all scores 0) and visiting all 20 neighbors.
    const bool allmask = (mbits == 0u);
    if (allmask) mbits = 0xFFFFFu;
    const float qz = allmask ? 0.f : 1.f;

    auto ldq = [&](int so) {
      const ushort4 u = *reinterpret_cast<const ushort4*>(qrow + so);
      return make_float4(bf2f(u.x) * qz, bf2f(u.y) * qz, bf2f(u.z) * qz, bf2f(u.w) * qz);
    };
    const float4 q00 = ldq(4 * l);
    const float4 q01 = v1 ? ldq(256 + 4 * l) : z4;
    const float4 q10 = ldq(448 + 4 * l);
    const float4 q11 = v1 ? ldq(448 + 256 + 4 * l) : z4;

    auto ldkv = [&](int n, float4& k0, float4& k1) {
      const size_t row = (size_t)b * kN + n;
      k0 = (l < 43) ? nnode4[row * 43 + l] : nedge4[row * 43 + (l - 43)];
      k1 = z4;
      if (v1) {
        const int j4 = 64 + l;
        k1 = (j4 < 86) ? nedge4[row * 43 + (j4 - 43)] : ntime4[row * 25 + (j4 - 86)];
      }
    };

    float4 va00 = z4, va01 = z4, va10 = z4, va11 = z4;
    float m0s = -1e30f, m1s = -1e30f, l0 = 0.f, l1 = 0.f;

    auto step = [&](const float4& kv0, const float4& kv1) {
      float ps0 = fma4(q01, kv1, fma4(q00, kv0, 0.f));
      float ps1 = fma4(q11, kv1, fma4(q10, kv0, 0.f));
      const float s0 = rdl63(dpp_sum(ps0)) * kScale;
      const float s1 = rdl63(dpp_sum(ps1)) * kScale;
      {
        const float mn = fmaxf(m0s, s0);
        const float al = __expf(m0s - mn);
        const float p = __expf(s0 - mn);
        l0 = l0 * al + p;
        m0s = mn;
        va00.x = fmaf(p, kv0.x, va00.x * al);
        va00.y = fmaf(p, kv0.y, va00.y * al);
        va00.z = fmaf(p, kv0.z, va00.z * al);
        va00.w = fmaf(p, kv0.w, va00.w * al);
        va01.x = fmaf(p, kv1.x, va01.x * al);
        va01.y = fmaf(p, kv1.y, va01.y * al);
        va01.z = fmaf(p, kv1.z, va01.z * al);
        va01.w = fmaf(p, kv1.w, va01.w * al);
      }
      {
        const float mn = fmaxf(m1s, s1);
        const float al = __expf(m1s - mn);
        const float p = __expf(s1 - mn);
        l1 = l1 * al + p;
        m1s = mn;
        va10.x = fmaf(p, kv0.x, va10.x * al);
        va10.y = fmaf(p, kv0.y, va10.y * al);
        va10.z = fmaf(p, kv0.z, va10.z * al);
        va10.w = fmaf(p, kv0.w, va10.w * al);
        va11.x = fmaf(p, kv1.x, va11.x * al);
        va11.y = fmaf(p, kv1.y, va11.y * al);
        va11.z = fmaf(p, kv1.z, va11.z * al);
        va11.w = fmaf(p, kv1.w, va11.w * al);
      }
    };

    // rotating 2-stage prefetch over compacted unmasked list (wave-uniform)
    unsigned rem = mbits;
    float4 a0k, a1k, c0k, c1k;
    {
      const int n0 = __builtin_ctz(rem);
      rem &= rem - 1;
      ldkv(n0, a0k, a1k);
    }
    for (;;) {
      int nB = -1;
      if (rem) {
        nB = __builtin_ctz(rem);
        rem &= rem - 1;
        ldkv(nB, c0k, c1k);  // in flight during step(A)
      }
      step(a0k, a1k);
      if (nB < 0) break;
      int nC = -1;
      if (rem) {
        nC = __builtin_ctz(rem);
        rem &= rem - 1;
        ldkv(nC, a0k, a1k);  // in flight during step(B)
      }
      step(c0k, c1k);
      if (nC < 0) break;
    }

    const float i0 = rfl(1.0f / l0);
    const float i1 = rfl(1.0f / l1);
    auto stq = [&](int so, float4 v, float s) {
      ushort4 u;
      u.x = f2bf(v.x * s); u.y = f2bf(v.y * s); u.z = f2bf(v.z * s); u.w = f2bf(v.w * s);
      *reinterpret_cast<ushort4*>(qrow + so) = u;
    };
    stq(4 * l, va00, i0);
    if (v1) stq(256 + 4 * l, va01, i0);
    stq(448 + 4 * l, va10, i1);
    if (v1) stq(448 + 256 + 4 * l, va11, i1);
  }
  __syncthreads();

  // ===== P3: X = v~ @ Pmat + bias + residual + LN ========================
  {
    const int koff = (l >> 4) * 8;
    f4v acc[2];
    acc[0] = (f4v){0.f, 0.f, 0.f, 0.f};
    acc[1] = (f4v){0.f, 0.f, 0.f, 0.f};
    for (int ks = 0; ks < 28; ++ks) {
      const s8v aA = *reinterpret_cast<const s8v*>(qlds + (size_t)(l & 15) * kQS + ks * 32 + koff);
#pragma unroll
      for (int i = 0; i < 2; ++i) {
        const int t = w + 16 * i;
        if (t < 17) {
          const s8v bfr = *reinterpret_cast<const s8v*>(Psw + ((size_t)(t * 28 + ks) * 64 + l) * 8);
          acc[i] = __builtin_amdgcn_mfma_f32_16x16x32_bf16(aA, bfr, acc[i], 0, 0, 0);
        }
      }
    }
    __syncthreads();  // all v~ reads done; qlds reusable as LN stage
    float* xl = reinterpret_cast<float*>(qlds);  // [16][273] = 17,472 B
    const int r0 = (l >> 4) * 4;
#pragma unroll
    for (int i = 0; i < 2; ++i) {
      const int t = w + 16 * i;
      if (t < 17) {
#pragma unroll
        for (int r = 0; r < 4; ++r)
          xl[(size_t)(r0 + r) * 273 + t * 16 + (l & 15)] = acc[i][r];
      }
    }
    __syncthreads();
    // LN: wave w -> row w
    const int b = m0 + w;
    float v[5];
    float sum = 0.f, sq = 0.f;
#pragma unroll
    for (int k = 0; k < 5; ++k) {
      const int o = l + 64 * k;
      v[k] = 0.f;
      if (o < 272) {
        const float r = (o < 172) ? node[(size_t)b * 172 + o] : timef[(size_t)b * 100 + (o - 172)];
        const float x = xl[(size_t)w * 273 + o] + bO[o] + r;
        v[k] = x;
        sum += x;
        sq = fmaf(x, x, sq);
      }
    }
#pragma unroll
    for (int off = 32; off >= 1; off >>= 1) {
      sum += __shfl_xor(sum, off, 64);
      sq += __shfl_xor(sq, off, 64);
    }
    const float mu = sum * (1.0f / 272.0f);
    const float var = sq * (1.0f / 272.0f) - mu * mu;
    const float rs = rsqrtf(var + kLnEps);
#pragma unroll
    for (int k = 0; k < 5; ++k) {
      const int o = l + 64 * k;
      if (o < 272) out[(size_t)b * 272 + o] = (v[k] - mu) * rs * g[o] + be[o];
    }
  }
}

extern "C" void kernel_launch(void* const* d_in, const int* in_sizes, int n_in,
                              void* d_out, int out_size, void* d_ws, size_t ws_size,
                              hipStream_t stream) {
  const float* node = (const float*)d_in[0];
  const float* timef = (const float*)d_in[1];
  const float* nnode = (const float*)d_in[2];
  const float* ntime = (const float*)d_in[3];
  const float* nedge = (const float*)d_in[4];
  const int* mask = (const int*)d_in[5];
  const float* WQ = (const float*)d_in[6];
  const float* WK = (const float*)d_in[7];
  const float* WV = (const float*)d_in[8];
  const float* WO = (const float*)d_in[9];
  const float* bO = (const float*)d_in[10];
  const float* g = (const float*)d_in[11];
  const float* be = (const float*)d_in[12];

  char* ws = (char*)d_ws;
  unsigned short* Msw = (unsigned short*)(ws + kOffMsw);
  unsigned short* Psw = (unsigned short*)(ws + kOffPsw);
  float* out = (float*)d_out;

  hipLaunchKernelGGL(k_build_mp, dim3(kMswBlocks + kPswBlocks), dim3(64), 0, stream,
                     WQ, WK, WO, WV, Msw, Psw);
  hipLaunchKernelGGL(k_fused, dim3(kB / 16), dim3(1024), 0, stream,
                     node, timef, nnode, nedge, ntime, mask, Msw, Psw, bO, g, be, out);
}

// Round 20
// 203.407 us; speedup vs baseline: 1.0179x; 1.0179x over previous
//
#include <hip/hip_runtime.h>

// TemporalAttention, algebraically folded; single fused per-16-row kernel.
//   builder: Msw/Psw weight folds.
//   k_fused (1024 thr = 16 waves, 16 rows/block, q~/v~ live in LDS):
//     P1: q~[16][896] = bf16(q) @ Mmat (MFMA; 56 N-tiles over 16 waves)
//     P2: attn, wave w owns row w; masked neighbors skipped; unmasked list
//         walked pairwise (B's loads in flight during A's compute, no
//         cross-iteration register rotation -> no spills)
//     P3: X = v~ @ Pmat + bias + residual + LN (MFMA; 17 tiles / 16 waves)
// Column layout jj' = h*448 + j (j<444 valid, pads zeroed via Msw/Psw).

namespace {
constexpr int kB = 16384;
constexpr int kN = 20;
constexpr float kScale = 0.08574929257125441f;  // 1/sqrt(136)
constexpr float kLnEps = 1e-5f;
constexpr int kQS = 904;  // LDS row stride (ushort); 1808B -> 2-way banks max

// ws byte offsets
constexpr size_t kOffMsw = 0;                // ushort[56*9*64*8]
constexpr size_t kOffPsw = kOffMsw + 516096; // ushort[17*28*64*8]

constexpr int kMswBlocks = 56 * 9 * 8;       // 4032
constexpr int kPswBlocks = 17 * 28 * 8;      // 3808
}  // namespace

typedef __attribute__((ext_vector_type(8))) short s8v;
typedef __attribute__((ext_vector_type(4))) float f4v;

__device__ __forceinline__ unsigned short f2bf(float x) {
  unsigned int u = __float_as_uint(x);
  unsigned int r = (u + 0x7FFFu + ((u >> 16) & 1u)) >> 16;
  return (unsigned short)r;
}
__device__ __forceinline__ float bf2f(unsigned short h) {
  return __uint_as_float(((unsigned int)h) << 16);
}
__device__ __forceinline__ float fma4(float4 a, float4 b, float acc) {
  acc = fmaf(a.x, b.x, acc);
  acc = fmaf(a.y, b.y, acc);
  acc = fmaf(a.z, b.z, acc);
  acc = fmaf(a.w, b.w, acc);
  return acc;
}
__device__ __forceinline__ s8v pack8(float4 lo, float4 hi) {
  s8v a;
  a[0] = (short)f2bf(lo.x); a[1] = (short)f2bf(lo.y);
  a[2] = (short)f2bf(lo.z); a[3] = (short)f2bf(lo.w);
  a[4] = (short)f2bf(hi.x); a[5] = (short)f2bf(hi.y);
  a[6] = (short)f2bf(hi.z); a[7] = (short)f2bf(hi.w);
  return a;
}

// ---- DPP wave64 sum (VALU only; full sum lands in lane 63) ----
__device__ __forceinline__ float dpp_sum(float x) {
  int v = __float_as_int(x), t;
  t = __builtin_amdgcn_update_dpp(0, v, 0x111, 0xf, 0xf, true);  // row_shr:1
  v = __float_as_int(__int_as_float(v) + __int_as_float(t));
  t = __builtin_amdgcn_update_dpp(0, v, 0x112, 0xf, 0xf, true);  // row_shr:2
  v = __float_as_int(__int_as_float(v) + __int_as_float(t));
  t = __builtin_amdgcn_update_dpp(0, v, 0x114, 0xf, 0xf, true);  // row_shr:4
  v = __float_as_int(__int_as_float(v) + __int_as_float(t));
  t = __builtin_amdgcn_update_dpp(0, v, 0x118, 0xf, 0xf, true);  // row_shr:8
  v = __float_as_int(__int_as_float(v) + __int_as_float(t));
  t = __builtin_amdgcn_update_dpp(0, v, 0x142, 0xf, 0xf, true);  // row_bcast:15
  v = __float_as_int(__int_as_float(v) + __int_as_float(t));
  t = __builtin_amdgcn_update_dpp(0, v, 0x143, 0xf, 0xf, true);  // row_bcast:31
  v = __float_as_int(__int_as_float(v) + __int_as_float(t));
  return __int_as_float(v);
}
__device__ __forceinline__ float rdl63(float x) {
  return __int_as_float(__builtin_amdgcn_readlane(__float_as_int(x), 63));
}
__device__ __forceinline__ float rfl(float x) {
  return __int_as_float(__builtin_amdgcn_readfirstlane(__float_as_int(x)));
}

// Merged weight-fold: blocks [0, kMswBlocks) build Msw, rest build Psw.
__global__ __launch_bounds__(64) void k_build_mp(const float* __restrict__ WQ,
                                                 const float* __restrict__ WK,
                                                 const float* __restrict__ WO,
                                                 const float* __restrict__ WV,
                                                 unsigned short* __restrict__ Msw,
                                                 unsigned short* __restrict__ Psw) {
  const int l = threadIdx.x;
  if (blockIdx.x < kMswBlocks) {
    const int bid = blockIdx.x;
    const int e = bid % 8;
    const int ks = (bid / 8) % 9;
    const int tile = bid / 72;
    const int jj = tile * 16 + (l & 15);
    const int h = jj / 448;
    const int j = jj - h * 448;
    const int i = ks * 32 + (l >> 4) * 8 + e;
    float s = 0.f;
    if (j < 444 && i < 272) {
      const float* wq = WQ + h * 136 * 272 + i;
      const float* wk = WK + h * 136 * 444 + j;
#pragma unroll 8
      for (int d = 0; d < 136; ++d) s = fmaf(wq[d * 272], wk[d * 444], s);
    }
    Msw[((size_t)(tile * 9 + ks) * 64 + l) * 8 + e] = f2bf(s);
  } else {
    const int bid = blockIdx.x - kMswBlocks;
    const int e = bid % 8;
    const int ks = (bid / 8) % 28;
    const int tile = bid / 224;
    const int n = tile * 16 + (l & 15);
    const int k = ks * 32 + (l >> 4) * 8 + e;
    const int h = k / 448;
    const int j = k - h * 448;
    float s = 0.f;
    if (j < 444) {
      const float* wo = WO + (size_t)n * 272 + h * 136;
      const float* wv = WV + h * 136 * 444 + j;
#pragma unroll 8
      for (int d = 0; d < 136; ++d) s = fmaf(wo[d], wv[d * 444], s);
    }
    Psw[((size_t)(tile * 28 + ks) * 64 + l) * 8 + e] = f2bf(s);
  }
}

// Fused 16-row pipeline; 16 waves; q~/v~ in LDS only.
__global__ __launch_bounds__(1024, 8) void k_fused(const float* __restrict__ node,
                                                   const float* __restrict__ timef,
                                                   const float* __restrict__ nnode,
                                                   const float* __restrict__ nedge,
                                                   const float* __restrict__ ntime,
                                                   const int* __restrict__ mask,
                                                   const unsigned short* __restrict__ Msw,
                                                   const unsigned short* __restrict__ Psw,
                                                   const float* __restrict__ bO,
                                                   const float* __restrict__ g,
                                                   const float* __restrict__ be,
                                                   float* __restrict__ out) {
  __shared__ unsigned short qlds[16 * kQS];  // 28,928 B; reused as LN stage
  const int tid = threadIdx.x;
  const int l = tid & 63, w = tid >> 6;  // w in 0..15
  const int m0 = blockIdx.x * 16;
  const float4 z4 = make_float4(0.f, 0.f, 0.f, 0.f);

  // ===== P1: q~ = bf16(q) @ Mmat -> qlds ================================
  {
    const int mrow = m0 + (l & 15);
    const int koff = (l >> 4) * 8;
    const float4* n4 = reinterpret_cast<const float4*>(node + (size_t)mrow * 172);
    const float4* t4 = reinterpret_cast<const float4*>(timef + (size_t)mrow * 100);
    f4v acc[4];
#pragma unroll
    for (int i = 0; i < 4; ++i) acc[i] = (f4v){0.f, 0.f, 0.f, 0.f};
    for (int ks = 0; ks < 9; ++ks) {
      const int c0 = ks * 32 + koff;
      float4 lo = z4, hi = z4;
      if (c0 + 8 <= 172) {
        lo = n4[c0 / 4];
        hi = n4[c0 / 4 + 1];
      } else if (c0 == 168) {
        lo = n4[42];
        hi = t4[0];
      } else if (c0 + 8 <= 272) {
        lo = t4[(c0 - 172) / 4];
        hi = t4[(c0 - 172) / 4 + 1];
      }
      const s8v a = pack8(lo, hi);
#pragma unroll
      for (int i = 0; i < 4; ++i) {
        const int t = w + 16 * i;
        if (t < 56) {
          const s8v b = *reinterpret_cast<const s8v*>(Msw + ((size_t)(t * 9 + ks) * 64 + l) * 8);
          acc[i] = __builtin_amdgcn_mfma_f32_16x16x32_bf16(a, b, acc[i], 0, 0, 0);
        }
      }
    }
    const int r0 = (l >> 4) * 4;
#pragma unroll
    for (int i = 0; i < 4; ++i) {
      const int t = w + 16 * i;
      if (t < 56) {
        const int n = t * 16 + (l & 15);
#pragma unroll
        for (int r = 0; r < 4; ++r) qlds[(size_t)(r0 + r) * kQS + n] = f2bf(acc[i][r]);
      }
    }
  }
  __syncthreads();

  // ===== P2: attn, wave w -> row m0+w; mask-skip + pairwise prefetch =====
  {
    const int b = m0 + w;
    const bool v1 = (l < 47);
    const float4* nnode4 = reinterpret_cast<const float4*>(nnode);
    const float4* nedge4 = reinterpret_cast<const float4*>(nedge);
    const float4* ntime4 = reinterpret_cast<const float4*>(ntime);
    unsigned short* qrow = qlds + (size_t)w * kQS;
    const int* mrow = mask + (size_t)b * kN;

    auto ldq = [&](int so) {
      const ushort4 u = *reinterpret_cast<const ushort4*>(qrow + so);
      return make_float4(bf2f(u.x), bf2f(u.y), bf2f(u.z), bf2f(u.w));
    };
    const float4 q00 = ldq(4 * l);
    const float4 q01 = v1 ? ldq(256 + 4 * l) : z4;
    const float4 q10 = ldq(448 + 4 * l);
    const float4 q11 = v1 ? ldq(448 + 256 + 4 * l) : z4;

    unsigned mbits = 0;
#pragma unroll
    for (int n = 0; n < kN; ++n) mbits |= (mrow[n] != 0 ? 1u : 0u) << n;

    auto ldkv = [&](int n, float4& k0, float4& k1) {
      const size_t row = (size_t)b * kN + n;
      k0 = (l < 43) ? nnode4[row * 43 + l] : nedge4[row * 43 + (l - 43)];
      k1 = z4;
      if (v1) {
        const int j4 = 64 + l;
        k1 = (j4 < 86) ? nedge4[row * 43 + (j4 - 43)] : ntime4[row * 25 + (j4 - 86)];
      }
    };

    float4 va00 = z4, va01 = z4, va10 = z4, va11 = z4;
    float i0, i1;

    if (mbits == 0u) {
      // all masked: softmax degenerates to uniform 1/20 over ALL neighbors.
#pragma unroll 1
      for (int n = 0; n < kN; ++n) {
        float4 kv0, kv1;
        ldkv(n, kv0, kv1);
        va00.x += kv0.x; va00.y += kv0.y; va00.z += kv0.z; va00.w += kv0.w;
        va01.x += kv1.x; va01.y += kv1.y; va01.z += kv1.z; va01.w += kv1.w;
      }
      va10 = va00;
      va11 = va01;
      i0 = 1.0f / 20.0f;
      i1 = 1.0f / 20.0f;
    } else {
      float m0s = -1e30f, m1s = -1e30f, l0 = 0.f, l1 = 0.f;

      auto step = [&](const float4& kv0, const float4& kv1) {
        float ps0 = fma4(q01, kv1, fma4(q00, kv0, 0.f));
        float ps1 = fma4(q11, kv1, fma4(q10, kv0, 0.f));
        const float s0 = rdl63(dpp_sum(ps0)) * kScale;
        const float s1 = rdl63(dpp_sum(ps1)) * kScale;
        {
          const float mn = fmaxf(m0s, s0);
          const float al = __expf(m0s - mn);
          const float p = __expf(s0 - mn);
          l0 = l0 * al + p;
          m0s = mn;
          va00.x = fmaf(p, kv0.x, va00.x * al);
          va00.y = fmaf(p, kv0.y, va00.y * al);
          va00.z = fmaf(p, kv0.z, va00.z * al);
          va00.w = fmaf(p, kv0.w, va00.w * al);
          va01.x = fmaf(p, kv1.x, va01.x * al);
          va01.y = fmaf(p, kv1.y, va01.y * al);
          va01.z = fmaf(p, kv1.z, va01.z * al);
          va01.w = fmaf(p, kv1.w, va01.w * al);
        }
        {
          const float mn = fmaxf(m1s, s1);
          const float al = __expf(m1s - mn);
          const float p = __expf(s1 - mn);
          l1 = l1 * al + p;
          m1s = mn;
          va10.x = fmaf(p, kv0.x, va10.x * al);
          va10.y = fmaf(p, kv0.y, va10.y * al);
          va10.z = fmaf(p, kv0.z, va10.z * al);
          va10.w = fmaf(p, kv0.w, va10.w * al);
          va11.x = fmaf(p, kv1.x, va11.x * al);
          va11.y = fmaf(p, kv1.y, va11.y * al);
          va11.z = fmaf(p, kv1.z, va11.z * al);
          va11.w = fmaf(p, kv1.w, va11.w * al);
        }
      };

      // pairwise: load A and B together; B's loads in flight during step(A).
      // No registers live across loop iterations -> no spill.
      unsigned rem = mbits;
      while (rem) {
        const int nA = __builtin_ctz(rem);
        rem &= rem - 1;
        int nB = -1;
        if (rem) {
          nB = __builtin_ctz(rem);
          rem &= rem - 1;
        }
        float4 a0k, a1k, b0k, b1k;
        ldkv(nA, a0k, a1k);
        if (nB >= 0) ldkv(nB, b0k, b1k);
        step(a0k, a1k);
        if (nB >= 0) step(b0k, b1k);
      }
      i0 = rfl(1.0f / l0);
      i1 = rfl(1.0f / l1);
    }

    auto stq = [&](int so, float4 v, float s) {
      ushort4 u;
      u.x = f2bf(v.x * s); u.y = f2bf(v.y * s); u.z = f2bf(v.z * s); u.w = f2bf(v.w * s);
      *reinterpret_cast<ushort4*>(qrow + so) = u;
    };
    stq(4 * l, va00, i0);
    if (v1) stq(256 + 4 * l, va01, i0);
    stq(448 + 4 * l, va10, i1);
    if (v1) stq(448 + 256 + 4 * l, va11, i1);
  }
  __syncthreads();

  // ===== P3: X = v~ @ Pmat + bias + residual + LN ========================
  {
    const int koff = (l >> 4) * 8;
    f4v acc[2];
    acc[0] = (f4v){0.f, 0.f, 0.f, 0.f};
    acc[1] = (f4v){0.f, 0.f, 0.f, 0.f};
    for (int ks = 0; ks < 28; ++ks) {
      const s8v aA = *reinterpret_cast<const s8v*>(qlds + (size_t)(l & 15) * kQS + ks * 32 + koff);
#pragma unroll
      for (int i = 0; i < 2; ++i) {
        const int t = w + 16 * i;
        if (t < 17) {
          const s8v bfr = *reinterpret_cast<const s8v*>(Psw + ((size_t)(t * 28 + ks) * 64 + l) * 8);
          acc[i] = __builtin_amdgcn_mfma_f32_16x16x32_bf16(aA, bfr, acc[i], 0, 0, 0);
        }
      }
    }
    __syncthreads();  // all v~ reads done; qlds reusable as LN stage
    float* xl = reinterpret_cast<float*>(qlds);  // [16][273] = 17,472 B
    const int r0 = (l >> 4) * 4;
#pragma unroll
    for (int i = 0; i < 2; ++i) {
      const int t = w + 16 * i;
      if (t < 17) {
#pragma unroll
        for (int r = 0; r < 4; ++r)
          xl[(size_t)(r0 + r) * 273 + t * 16 + (l & 15)] = acc[i][r];
      }
    }
    __syncthreads();
    // LN: wave w -> row w
    const int b = m0 + w;
    float v[5];
    float sum = 0.f, sq = 0.f;
#pragma unroll
    for (int k = 0; k < 5; ++k) {
      const int o = l + 64 * k;
      v[k] = 0.f;
      if (o < 272) {
        const float r = (o < 172) ? node[(size_t)b * 172 + o] : timef[(size_t)b * 100 + (o - 172)];
        const float x = xl[(size_t)w * 273 + o] + bO[o] + r;
        v[k] = x;
        sum += x;
        sq = fmaf(x, x, sq);
      }
    }
#pragma unroll
    for (int off = 32; off >= 1; off >>= 1) {
      sum += __shfl_xor(sum, off, 64);
      sq += __shfl_xor(sq, off, 64);
    }
    const float mu = sum * (1.0f / 272.0f);
    const float var = sq * (1.0f / 272.0f) - mu * mu;
    const float rs = rsqrtf(var + kLnEps);
#pragma unroll
    for (int k = 0; k < 5; ++k) {
      const int o = l + 64 * k;
      if (o < 272) out[(size_t)b * 272 + o] = (v[k] - mu) * rs * g[o] + be[o];
    }
  }
}

extern "C" void kernel_launch(void* const* d_in, const int* in_sizes, int n_in,
                              void* d_out, int out_size, void* d_ws, size_t ws_size,
                              hipStream_t stream) {
  const float* node = (const float*)d_in[0];
  const float* timef = (const float*)d_in[1];
  const float* nnode = (const float*)d_in[2];
  const float* ntime = (const float*)d_in[3];
  const float* nedge = (const float*)d_in[4];
  const int* mask = (const int*)d_in[5];
  const float* WQ = (const float*)d_in[6];
  const float* WK = (const float*)d_in[7];
  const float* WV = (const float*)d_in[8];
  const float* WO = (const float*)d_in[9];
  const float* bO = (const float*)d_in[10];
  const float* g = (const float*)d_in[11];
  const float* be = (const float*)d_in[12];

  char* ws = (char*)d_ws;
  unsigned short* Msw = (unsigned short*)(ws + kOffMsw);
  unsigned short* Psw = (unsigned short*)(ws + kOffPsw);
  float* out = (float*)d_out;

  hipLaunchKernelGGL(k_build_mp, dim3(kMswBlocks + kPswBlocks), dim3(64), 0, stream,
                     WQ, WK, WO, WV, Msw, Psw);
  hipLaunchKernelGGL(k_fused, dim3(kB / 16), dim3(1024), 0, stream,
                     node, timef, nnode, nedge, ntime, mask, Msw, Psw, bO, g, be, out);
}

// Round 21
// 174.345 us; speedup vs baseline: 1.1876x; 1.1667x over previous
//
#include <hip/hip_runtime.h>

// TemporalAttention, algebraically folded; single fused per-16-row kernel.
//   builder: Msw/Psw weight folds.
//   k_fused (1024 thr = 16 waves, 16 rows/block, q~/v~ live in LDS):
//     P1: q~[16][896] = bf16(q) @ Mmat (MFMA; 56 N-tiles over 16 waves)
//     P2: attn, wave w owns row w (full wave-per-row parallelism); masked
//         neighbors skipped (weight exactly 0 in fp32; all-masked -> uniform)
//     P3: X = v~ @ Pmat + bias + residual + LN (MFMA; 17 tiles / 16 waves)
// Column layout jj' = h*448 + j (j<444 valid, pads zeroed via Msw/Psw).
// NOTE: this is the measured-best variant (r18, 174.5 us). r19/r20 prefetch
// variants regressed (dynamic control flow defeats codegen); kept verbatim.

namespace {
constexpr int kB = 16384;
constexpr int kN = 20;
constexpr float kScale = 0.08574929257125441f;  // 1/sqrt(136)
constexpr float kLnEps = 1e-5f;
constexpr int kQS = 904;  // LDS row stride (ushort); 1808B -> 2-way banks max

// ws byte offsets
constexpr size_t kOffMsw = 0;                // ushort[56*9*64*8]
constexpr size_t kOffPsw = kOffMsw + 516096; // ushort[17*28*64*8]

constexpr int kMswBlocks = 56 * 9 * 8;       // 4032
constexpr int kPswBlocks = 17 * 28 * 8;      // 3808
}  // namespace

typedef __attribute__((ext_vector_type(8))) short s8v;
typedef __attribute__((ext_vector_type(4))) float f4v;

__device__ __forceinline__ unsigned short f2bf(float x) {
  unsigned int u = __float_as_uint(x);
  unsigned int r = (u + 0x7FFFu + ((u >> 16) & 1u)) >> 16;
  return (unsigned short)r;
}
__device__ __forceinline__ float bf2f(unsigned short h) {
  return __uint_as_float(((unsigned int)h) << 16);
}
__device__ __forceinline__ float fma4(float4 a, float4 b, float acc) {
  acc = fmaf(a.x, b.x, acc);
  acc = fmaf(a.y, b.y, acc);
  acc = fmaf(a.z, b.z, acc);
  acc = fmaf(a.w, b.w, acc);
  return acc;
}
__device__ __forceinline__ s8v pack8(float4 lo, float4 hi) {
  s8v a;
  a[0] = (short)f2bf(lo.x); a[1] = (short)f2bf(lo.y);
  a[2] = (short)f2bf(lo.z); a[3] = (short)f2bf(lo.w);
  a[4] = (short)f2bf(hi.x); a[5] = (short)f2bf(hi.y);
  a[6] = (short)f2bf(hi.z); a[7] = (short)f2bf(hi.w);
  return a;
}

// ---- DPP wave64 sum (VALU only; full sum lands in lane 63) ----
__device__ __forceinline__ float dpp_sum(float x) {
  int v = __float_as_int(x), t;
  t = __builtin_amdgcn_update_dpp(0, v, 0x111, 0xf, 0xf, true);  // row_shr:1
  v = __float_as_int(__int_as_float(v) + __int_as_float(t));
  t = __builtin_amdgcn_update_dpp(0, v, 0x112, 0xf, 0xf, true);  // row_shr:2
  v = __float_as_int(__int_as_float(v) + __int_as_float(t));
  t = __builtin_amdgcn_update_dpp(0, v, 0x114, 0xf, 0xf, true);  // row_shr:4
  v = __float_as_int(__int_as_float(v) + __int_as_float(t));
  t = __builtin_amdgcn_update_dpp(0, v, 0x118, 0xf, 0xf, true);  // row_shr:8
  v = __float_as_int(__int_as_float(v) + __int_as_float(t));
  t = __builtin_amdgcn_update_dpp(0, v, 0x142, 0xf, 0xf, true);  // row_bcast:15
  v = __float_as_int(__int_as_float(v) + __int_as_float(t));
  t = __builtin_amdgcn_update_dpp(0, v, 0x143, 0xf, 0xf, true);  // row_bcast:31
  v = __float_as_int(__int_as_float(v) + __int_as_float(t));
  return __int_as_float(v);
}
__device__ __forceinline__ float rdl63(float x) {
  return __int_as_float(__builtin_amdgcn_readlane(__float_as_int(x), 63));
}
__device__ __forceinline__ float rfl(float x) {
  return __int_as_float(__builtin_amdgcn_readfirstlane(__float_as_int(x)));
}

// Merged weight-fold: blocks [0, kMswBlocks) build Msw, rest build Psw.
__global__ __launch_bounds__(64) void k_build_mp(const float* __restrict__ WQ,
                                                 const float* __restrict__ WK,
                                                 const float* __restrict__ WO,
                                                 const float* __restrict__ WV,
                                                 unsigned short* __restrict__ Msw,
                                                 unsigned short* __restrict__ Psw) {
  const int l = threadIdx.x;
  if (blockIdx.x < kMswBlocks) {
    const int bid = blockIdx.x;
    const int e = bid % 8;
    const int ks = (bid / 8) % 9;
    const int tile = bid / 72;
    const int jj = tile * 16 + (l & 15);
    const int h = jj / 448;
    const int j = jj - h * 448;
    const int i = ks * 32 + (l >> 4) * 8 + e;
    float s = 0.f;
    if (j < 444 && i < 272) {
      const float* wq = WQ + h * 136 * 272 + i;
      const float* wk = WK + h * 136 * 444 + j;
#pragma unroll 8
      for (int d = 0; d < 136; ++d) s = fmaf(wq[d * 272], wk[d * 444], s);
    }
    Msw[((size_t)(tile * 9 + ks) * 64 + l) * 8 + e] = f2bf(s);
  } else {
    const int bid = blockIdx.x - kMswBlocks;
    const int e = bid % 8;
    const int ks = (bid / 8) % 28;
    const int tile = bid / 224;
    const int n = tile * 16 + (l & 15);
    const int k = ks * 32 + (l >> 4) * 8 + e;
    const int h = k / 448;
    const int j = k - h * 448;
    float s = 0.f;
    if (j < 444) {
      const float* wo = WO + (size_t)n * 272 + h * 136;
      const float* wv = WV + h * 136 * 444 + j;
#pragma unroll 8
      for (int d = 0; d < 136; ++d) s = fmaf(wo[d], wv[d * 444], s);
    }
    Psw[((size_t)(tile * 28 + ks) * 64 + l) * 8 + e] = f2bf(s);
  }
}

// Fused 16-row pipeline; 16 waves; q~/v~ in LDS only.
__global__ __launch_bounds__(1024, 8) void k_fused(const float* __restrict__ node,
                                                   const float* __restrict__ timef,
                                                   const float* __restrict__ nnode,
                                                   const float* __restrict__ nedge,
                                                   const float* __restrict__ ntime,
                                                   const int* __restrict__ mask,
                                                   const unsigned short* __restrict__ Msw,
                                                   const unsigned short* __restrict__ Psw,
                                                   const float* __restrict__ bO,
                                                   const float* __restrict__ g,
                                                   const float* __restrict__ be,
                                                   float* __restrict__ out) {
  __shared__ unsigned short qlds[16 * kQS];  // 28,928 B; reused as LN stage
  const int tid = threadIdx.x;
  const int l = tid & 63, w = tid >> 6;  // w in 0..15
  const int m0 = blockIdx.x * 16;
  const float4 z4 = make_float4(0.f, 0.f, 0.f, 0.f);

  // ===== P1: q~ = bf16(q) @ Mmat -> qlds ================================
  {
    const int mrow = m0 + (l & 15);
    const int koff = (l >> 4) * 8;
    const float4* n4 = reinterpret_cast<const float4*>(node + (size_t)mrow * 172);
    const float4* t4 = reinterpret_cast<const float4*>(timef + (size_t)mrow * 100);
    f4v acc[4];
#pragma unroll
    for (int i = 0; i < 4; ++i) acc[i] = (f4v){0.f, 0.f, 0.f, 0.f};
    for (int ks = 0; ks < 9; ++ks) {
      const int c0 = ks * 32 + koff;
      float4 lo = z4, hi = z4;
      if (c0 + 8 <= 172) {
        lo = n4[c0 / 4];
        hi = n4[c0 / 4 + 1];
      } else if (c0 == 168) {
        lo = n4[42];
        hi = t4[0];
      } else if (c0 + 8 <= 272) {
        lo = t4[(c0 - 172) / 4];
        hi = t4[(c0 - 172) / 4 + 1];
      }
      const s8v a = pack8(lo, hi);
#pragma unroll
      for (int i = 0; i < 4; ++i) {
        const int t = w + 16 * i;
        if (t < 56) {
          const s8v b = *reinterpret_cast<const s8v*>(Msw + ((size_t)(t * 9 + ks) * 64 + l) * 8);
          acc[i] = __builtin_amdgcn_mfma_f32_16x16x32_bf16(a, b, acc[i], 0, 0, 0);
        }
      }
    }
    const int r0 = (l >> 4) * 4;
#pragma unroll
    for (int i = 0; i < 4; ++i) {
      const int t = w + 16 * i;
      if (t < 56) {
        const int n = t * 16 + (l & 15);
#pragma unroll
        for (int r = 0; r < 4; ++r) qlds[(size_t)(r0 + r) * kQS + n] = f2bf(acc[i][r]);
      }
    }
  }
  __syncthreads();

  // ===== P2: attn, wave w -> row m0+w; q~ read / v~ written in LDS row w =
  {
    const int b = m0 + w;
    const bool v1 = (l < 47);
    const float4* nnode4 = reinterpret_cast<const float4*>(nnode);
    const float4* nedge4 = reinterpret_cast<const float4*>(nedge);
    const float4* ntime4 = reinterpret_cast<const float4*>(ntime);
    unsigned short* qrow = qlds + (size_t)w * kQS;
    const int* mrow = mask + (size_t)b * kN;

    auto ldq = [&](int so) {
      const ushort4 u = *reinterpret_cast<const ushort4*>(qrow + so);
      return make_float4(bf2f(u.x), bf2f(u.y), bf2f(u.z), bf2f(u.w));
    };
    const float4 q00 = ldq(4 * l);
    const float4 q01 = v1 ? ldq(256 + 4 * l) : z4;
    const float4 q10 = ldq(448 + 4 * l);
    const float4 q11 = v1 ? ldq(448 + 256 + 4 * l) : z4;

    unsigned mbits = 0;
#pragma unroll
    for (int n = 0; n < kN; ++n) mbits |= (mrow[n] != 0 ? 1u : 0u) << n;

    auto ldkv = [&](int n, float4& k0, float4& k1) {
      const size_t row = (size_t)b * kN + n;
      k0 = (l < 43) ? nnode4[row * 43 + l] : nedge4[row * 43 + (l - 43)];
      k1 = z4;
      if (v1) {
        const int j4 = 64 + l;
        k1 = (j4 < 86) ? nedge4[row * 43 + (j4 - 43)] : ntime4[row * 25 + (j4 - 86)];
      }
    };

    float4 va00 = z4, va01 = z4, va10 = z4, va11 = z4;
    float i0, i1;

    if (mbits == 0u) {
#pragma unroll 1
      for (int n = 0; n < kN; ++n) {
        float4 kv0, kv1;
        ldkv(n, kv0, kv1);
        va00.x += kv0.x; va00.y += kv0.y; va00.z += kv0.z; va00.w += kv0.w;
        va01.x += kv1.x; va01.y += kv1.y; va01.z += kv1.z; va01.w += kv1.w;
      }
      va10 = va00;
      va11 = va01;
      i0 = 1.0f / 20.0f;
      i1 = 1.0f / 20.0f;
    } else {
      float m0s = -1e30f, m1s = -1e30f, l0 = 0.f, l1 = 0.f;
#pragma unroll
      for (int n = 0; n < kN; ++n) {
        if (!(mbits & (1u << n))) continue;  // masked: weight exactly 0
        float4 kv0, kv1;
        ldkv(n, kv0, kv1);
        float ps0 = fma4(q01, kv1, fma4(q00, kv0, 0.f));
        float ps1 = fma4(q11, kv1, fma4(q10, kv0, 0.f));
        const float sa0 = rdl63(dpp_sum(ps0));
        const float sa1 = rdl63(dpp_sum(ps1));
        const float s0 = sa0 * kScale;
        const float s1 = sa1 * kScale;
        {
          const float mn = fmaxf(m0s, s0);
          const float al = __expf(m0s - mn);
          const float p = __expf(s0 - mn);
          l0 = l0 * al + p;
          m0s = mn;
          va00.x = fmaf(p, kv0.x, va00.x * al);
          va00.y = fmaf(p, kv0.y, va00.y * al);
          va00.z = fmaf(p, kv0.z, va00.z * al);
          va00.w = fmaf(p, kv0.w, va00.w * al);
          va01.x = fmaf(p, kv1.x, va01.x * al);
          va01.y = fmaf(p, kv1.y, va01.y * al);
          va01.z = fmaf(p, kv1.z, va01.z * al);
          va01.w = fmaf(p, kv1.w, va01.w * al);
        }
        {
          const float mn = fmaxf(m1s, s1);
          const float al = __expf(m1s - mn);
          const float p = __expf(s1 - mn);
          l1 = l1 * al + p;
          m1s = mn;
          va10.x = fmaf(p, kv0.x, va10.x * al);
          va10.y = fmaf(p, kv0.y, va10.y * al);
          va10.z = fmaf(p, kv0.z, va10.z * al);
          va10.w = fmaf(p, kv0.w, va10.w * al);
          va11.x = fmaf(p, kv1.x, va11.x * al);
          va11.y = fmaf(p, kv1.y, va11.y * al);
          va11.z = fmaf(p, kv1.z, va11.z * al);
          va11.w = fmaf(p, kv1.w, va11.w * al);
        }
      }
      i0 = rfl(1.0f / l0);
      i1 = rfl(1.0f / l1);
    }

    auto stq = [&](int so, float4 v, float s) {
      ushort4 u;
      u.x = f2bf(v.x * s); u.y = f2bf(v.y * s); u.z = f2bf(v.z * s); u.w = f2bf(v.w * s);
      *reinterpret_cast<ushort4*>(qrow + so) = u;
    };
    stq(4 * l, va00, i0);
    if (v1) stq(256 + 4 * l, va01, i0);
    stq(448 + 4 * l, va10, i1);
    if (v1) stq(448 + 256 + 4 * l, va11, i1);
  }
  __syncthreads();

  // ===== P3: X = v~ @ Pmat + bias + residual + LN ========================
  {
    const int koff = (l >> 4) * 8;
    f4v acc[2];
    acc[0] = (f4v){0.f, 0.f, 0.f, 0.f};
    acc[1] = (f4v){0.f, 0.f, 0.f, 0.f};
    for (int ks = 0; ks < 28; ++ks) {
      const s8v aA = *reinterpret_cast<const s8v*>(qlds + (size_t)(l & 15) * kQS + ks * 32 + koff);
#pragma unroll
      for (int i = 0; i < 2; ++i) {
        const int t = w + 16 * i;
        if (t < 17) {
          const s8v bfr = *reinterpret_cast<const s8v*>(Psw + ((size_t)(t * 28 + ks) * 64 + l) * 8);
          acc[i] = __builtin_amdgcn_mfma_f32_16x16x32_bf16(aA, bfr, acc[i], 0, 0, 0);
        }
      }
    }
    __syncthreads();  // all v~ reads done; qlds reusable as LN stage
    float* xl = reinterpret_cast<float*>(qlds);  // [16][273] = 17,472 B
    const int r0 = (l >> 4) * 4;
#pragma unroll
    for (int i = 0; i < 2; ++i) {
      const int t = w + 16 * i;
      if (t < 17) {
#pragma unroll
        for (int r = 0; r < 4; ++r)
          xl[(size_t)(r0 + r) * 273 + t * 16 + (l & 15)] = acc[i][r];
      }
    }
    __syncthreads();
    // LN: wave w -> row w
    const int b = m0 + w;
    float v[5];
    float sum = 0.f, sq = 0.f;
#pragma unroll
    for (int k = 0; k < 5; ++k) {
      const int o = l + 64 * k;
      v[k] = 0.f;
      if (o < 272) {
        const float r = (o < 172) ? node[(size_t)b * 172 + o] : timef[(size_t)b * 100 + (o - 172)];
        const float x = xl[(size_t)w * 273 + o] + bO[o] + r;
        v[k] = x;
        sum += x;
        sq = fmaf(x, x, sq);
      }
    }
#pragma unroll
    for (int off = 32; off >= 1; off >>= 1) {
      sum += __shfl_xor(sum, off, 64);
      sq += __shfl_xor(sq, off, 64);
    }
    const float mu = sum * (1.0f / 272.0f);
    const float var = sq * (1.0f / 272.0f) - mu * mu;
    const float rs = rsqrtf(var + kLnEps);
#pragma unroll
    for (int k = 0; k < 5; ++k) {
      const int o = l + 64 * k;
      if (o < 272) out[(size_t)b * 272 + o] = (v[k] - mu) * rs * g[o] + be[o];
    }
  }
}

extern "C" void kernel_launch(void* const* d_in, const int* in_sizes, int n_in,
                              void* d_out, int out_size, void* d_ws, size_t ws_size,
                              hipStream_t stream) {
  const float* node = (const float*)d_in[0];
  const float* timef = (const float*)d_in[1];
  const float* nnode = (const float*)d_in[2];
  const float* ntime = (const float*)d_in[3];
  const float* nedge = (const float*)d_in[4];
  const int* mask = (const int*)d_in[5];
  const float* WQ = (const float*)d_in[6];
  const float* WK = (const float*)d_in[7];
  const float* WV = (const float*)d_in[8];
  const float* WO = (const float*)d_in[9];
  const float* bO = (const float*)d_in[10];
  const float* g = (const float*)d_in[11];
  const float* be = (const float*)d_in[12];

  char* ws = (char*)d_ws;
  unsigned short* Msw = (unsigned short*)(ws + kOffMsw);
  unsigned short* Psw = (unsigned short*)(ws + kOffPsw);
  float* out = (float*)d_out;

  hipLaunchKernelGGL(k_build_mp, dim3(kMswBlocks + kPswBlocks), dim3(64), 0, stream,
                     WQ, WK, WO, WV, Msw, Psw);
  hipLaunchKernelGGL(k_fused, dim3(kB / 16), dim3(1024), 0, stream,
                     node, timef, nnode, nedge, ntime, mask, Msw, Psw, bO, g, be, out);
}